// Round 5
// baseline (586.295 us; speedup 1.0000x reference)
//
#include <hip/hip_runtime.h>
#include <math.h>

// ---------------------------------------------------------------------------
// MultiLoss + JSD fused pipeline. R5: collapse the kernel chain.
// R1-R4 evidence: k_main 190->137 us but TOTAL stuck at ~446 with a CONSTANT
// ~309 us residual across all rounds -> the serialized small-grid aux chain
// (init/minmax/hist/merge/final) is the real cost. New structure:
//   K1 k_part   (352 blks): partial min/max + m/f counts (no atomics, no
//                init dependency) + zeroes hist/sum cells.
//   K2 k_reduce (1 blk)   : finalize min/max/counts.
//   K3 k_fused  (4096 blks): R4 quad-per-row streaming-CE main loss, PLUS
//                each block histograms its own 64 rows directly into the
//                merged global hist via atomics (640 atomics/blk over 16k
//                addresses, overlapped with main compute; no LDS hist ->
//                occupancy unchanged).
//   K4 k_final  (1 blk)   : KL over merged hist + combine.
// ---------------------------------------------------------------------------

#define BINS 800
#define NHCOLS 10
#define PB 352            // k_part blocks; 352*256 = 90112 = 11*8192

// workspace layout (uint32 indices)
#define MIN_OFF 0         // 11 ordered-uint mins (written by k_reduce)
#define MAX_OFF 16        // 11 ordered-uint maxs
#define CNT_OFF 32        // male, female counts
#define SUM_OFF 34        // mse_sum, ce_sum (float)
#define MH_OFF  64        // 8000 male hist   (zeroed by k_part)
#define FH_OFF  8064      // 8000 female hist (zeroed by k_part)
#define PART_OFF 16384    // PB x 24 partial records (11 min, 11 max, 2 cnt)

__device__ __forceinline__ unsigned f2ord(float f) {
  unsigned u = __float_as_uint(f);
  return (u & 0x80000000u) ? ~u : (u | 0x80000000u);
}
__device__ __forceinline__ float ord2f(unsigned e) {
  return __uint_as_float((e & 0x80000000u) ? (e & 0x7FFFFFFFu) : ~e);
}

// K1: per-block partial min/max/count (no global atomics) + zero hist/sums.
__global__ __launch_bounds__(256) void k_part(const float* __restrict__ enc,
                                              const float* __restrict__ lab,
                                              unsigned* __restrict__ ws, int B) {
  const int tid    = blockIdx.x * 256 + threadIdx.x;
  const int stride = PB * 256;                 // 90112 = 11*8192
  // zero the cells later kernels accumulate into
  if (tid < 2) ws[SUM_OFF + tid] = 0u;
  for (int i = tid; i < 2 * BINS * NHCOLS; i += stride) ws[MH_OFF + i] = 0u;
  const int c = tid % 11;
  unsigned mn = 0xFFFFFFFFu, mx = 0u;
  const long long total = (long long)B * 11;
  for (long long i = tid; i < total; i += stride) {
    unsigned e = f2ord(enc[i]);
    mn = mn < e ? mn : e;
    mx = mx > e ? mx : e;
  }
  unsigned m = 0, f = 0;
  for (int i = tid; i < B; i += stride) {
    float v = lab[i];
    m += (v == 0.0f);
    f += (v == 1.0f);
  }
  __shared__ unsigned smn[11], smx[11], scnt[2];
  if (threadIdx.x < 11) { smn[threadIdx.x] = 0xFFFFFFFFu; smx[threadIdx.x] = 0u; }
  if (threadIdx.x < 2)  scnt[threadIdx.x] = 0u;
  __syncthreads();
  atomicMin(&smn[c], mn);
  atomicMax(&smx[c], mx);
  atomicAdd(&scnt[0], m);
  atomicAdd(&scnt[1], f);
  __syncthreads();
  unsigned* rec = ws + PART_OFF + blockIdx.x * 24;
  if (threadIdx.x < 11) {
    rec[threadIdx.x]      = smn[threadIdx.x];
    rec[11 + threadIdx.x] = smx[threadIdx.x];
  }
  if (threadIdx.x < 2) rec[22 + threadIdx.x] = scnt[threadIdx.x];
}

// K2: reduce PB partial records -> final min/max/counts.
__global__ __launch_bounds__(384) void k_reduce(unsigned* __restrict__ ws) {
  __shared__ unsigned smn[11], smx[11], scnt[2];
  if (threadIdx.x < 11) { smn[threadIdx.x] = 0xFFFFFFFFu; smx[threadIdx.x] = 0u; }
  if (threadIdx.x < 2)  scnt[threadIdx.x] = 0u;
  __syncthreads();
  for (int p = threadIdx.x; p < PB; p += blockDim.x) {
    const unsigned* rec = ws + PART_OFF + p * 24;
#pragma unroll
    for (int c = 0; c < 11; ++c) {
      atomicMin(&smn[c], rec[c]);
      atomicMax(&smx[c], rec[11 + c]);
    }
    atomicAdd(&scnt[0], rec[22]);
    atomicAdd(&scnt[1], rec[23]);
  }
  __syncthreads();
  if (threadIdx.x < 11) {
    ws[MIN_OFF + threadIdx.x] = smn[threadIdx.x];
    ws[MAX_OFF + threadIdx.x] = smx[threadIdx.x];
  }
  if (threadIdx.x < 2) ws[CNT_OFF + threadIdx.x] = scnt[threadIdx.x];
}

// ---- column classification (compile-time) ----
__host__ __device__ constexpr int slice_of(int c) {
  return (c>=1&&c<10)?0:(c>=12&&c<29)?1:(c>=30&&c<33)?2:(c>=33&&c<40)?3:
         (c>=40&&c<64)?4:(c>=64&&c<79)?5:(c>=79&&c<84)?6:(c>=84&&c<94)?7:
         (c>=94&&c<96)?8:(c>=96&&c<99)?9:(c>=99&&c<105)?10:(c>=105&&c<113)?11:
         (c>=116&&c<122)?12:(c>=122&&c<128)?13:(c>=128&&c<151)?14:
         (c>=151&&c<159)?15:(c>=160&&c<165)?16:-1;
}
__host__ __device__ constexpr bool mse_of(int c) {
  return c==0||c==10||c==11||c==29||c==113||c==114||c==115||c==159||
         c==165||c==166||c==167;
}

template<int I, int K>
__device__ __forceinline__ void elem(const float (&d)[11][4], const float (&t)[11][4],
                                     float (&s)[17], float &dot, float &mse, int j) {
  constexpr int c0 = 16*I + K, c1 = c0+4, c2 = c0+8, c3 = c0+12;
  constexpr int cem = ((c0<168 && slice_of(c0)>=0)?1:0) |
                      ((c1<168 && slice_of(c1)>=0)?2:0) |
                      ((c2<168 && slice_of(c2)>=0)?4:0) |
                      ((c3<168 && slice_of(c3)>=0)?8:0);
  constexpr int msm = ((c0<168 && mse_of(c0))?1:0) | ((c1<168 && mse_of(c1))?2:0) |
                      ((c2<168 && mse_of(c2))?4:0) | ((c3<168 && mse_of(c3))?8:0);
  const float dv = d[I][K], tv = t[I][K];
  if constexpr (cem != 0) {
    float e = __expf(dv);
    if constexpr (cem & 1) s[slice_of(c0)] += (j == 0) ? e : 0.0f;
    if constexpr (cem & 2) s[slice_of(c1)] += (j == 1) ? e : 0.0f;
    if constexpr (cem & 4) s[slice_of(c2)] += (j == 2) ? e : 0.0f;
    if constexpr (cem & 8) s[slice_of(c3)] += (j == 3) ? e : 0.0f;
    dot += ((cem >> j) & 1) ? tv * dv : 0.0f;
  }
  if constexpr (msm != 0) {
    float df = dv - tv;
    mse += ((msm >> j) & 1) ? df * df : 0.0f;
  }
}

template<int I>
__device__ __forceinline__ void elem_row(const float (&d)[11][4], const float (&t)[11][4],
                                         float (&s)[17], float &dot, float &mse, int j) {
  elem<I,0>(d, t, s, dot, mse, j);
  elem<I,1>(d, t, s, dot, mse, j);
  elem<I,2>(d, t, s, dot, mse, j);
  elem<I,3>(d, t, s, dot, mse, j);
}

// K3: quad-per-row main loss (streaming CE) + per-block direct-to-global
// histogram of the block's own rows (overlapped with main compute).
__global__ __launch_bounds__(256) void k_fused(const float* __restrict__ dec,
                                               const float* __restrict__ tru,
                                               const float* __restrict__ enc,
                                               const float* __restrict__ lab,
                                               unsigned* __restrict__ ws, int B) {
  float* wsf = (float*)ws;
  const int lane = threadIdx.x & 63;
  const int wid  = threadIdx.x >> 6;
  const int j    = lane & 3;
  const int row  = blockIdx.x * 64 + (wid << 4) + (lane >> 2);
  const bool valid = row < B;

  // ---- issue main loads first (quad-contiguous 64B segments) ----
  float d[11][4], t[11][4];
  const float4* d4 = (const float4*)(dec + (size_t)row * 168);
  const float4* t4 = (const float4*)(tru + (size_t)row * 168);
#pragma unroll
  for (int i = 0; i < 11; ++i) {
    const int w = 4 * i + j;
    float4 dv = make_float4(0.f, 0.f, 0.f, 0.f);
    float4 tv = make_float4(0.f, 0.f, 0.f, 0.f);
    if (valid && w < 42) { dv = d4[w]; tv = t4[w]; }
    d[i][0] = dv.x; d[i][1] = dv.y; d[i][2] = dv.z; d[i][3] = dv.w;
    t[i][0] = tv.x; t[i][1] = tv.y; t[i][2] = tv.z; t[i][3] = tv.w;
  }

  // ---- histogram of this block's rows (lane j handles 2-3 of 10 cols) ----
  // j=0:{0,1,2} j=1:{3,4,5} j=2:{6,7} j=3:{8,9}
  {
    const int c0 = (j < 2) ? 3 * j : (6 + 2 * (j - 2));
    const int nc = (j < 2) ? 3 : 2;
    float lv = valid ? lab[row] : -1.0f;
    unsigned base = (lv == 0.0f) ? MH_OFF : ((lv == 1.0f) ? FH_OFF : 0u);
    if (base) {
#pragma unroll
      for (int k = 0; k < 3; ++k) {
        if (k < nc) {
          int c = c0 + k;
          float mnv = ord2f(ws[MIN_OFF + c]);
          float mxv = ord2f(ws[MAX_OFF + c]);
          float x = enc[(size_t)row * 11 + c];
          float tt = (x - mnv) / (mxv - mnv);   // IEEE div, matches numpy
          int b = (int)floorf(tt * 800.0f);
          b = b < 0 ? 0 : (b > BINS - 1 ? BINS - 1 : b);
          atomicAdd(&ws[base + c * BINS + b], 1u);
        }
      }
    }
  }

  // ---- main loss ----
  float s[17];
#pragma unroll
  for (int k = 0; k < 17; ++k) s[k] = 0.0f;
  float dot = 0.0f, mse = 0.0f;

  elem_row<0>(d, t, s, dot, mse, j);
  elem_row<1>(d, t, s, dot, mse, j);
  elem_row<2>(d, t, s, dot, mse, j);
  elem_row<3>(d, t, s, dot, mse, j);
  elem_row<4>(d, t, s, dot, mse, j);
  elem_row<5>(d, t, s, dot, mse, j);
  elem_row<6>(d, t, s, dot, mse, j);
  elem_row<7>(d, t, s, dot, mse, j);
  elem_row<8>(d, t, s, dot, mse, j);
  elem_row<9>(d, t, s, dot, mse, j);
  elem_row<10>(d, t, s, dot, mse, j);

  dot += __shfl_xor(dot, 1, 64);
  dot += __shfl_xor(dot, 2, 64);
#pragma unroll
  for (int k = 0; k < 17; ++k) {
    s[k] += __shfl_xor(s[k], 1, 64);
    s[k] += __shfl_xor(s[k], 2, 64);
  }
  float ce = -dot;
#pragma unroll
  for (int k = 0; k < 17; ++k) ce += __logf(s[k]);

  ce  = (valid && j == 0) ? ce : 0.0f;
  mse = valid ? mse : 0.0f;

  __shared__ float sm[4], sc[4];
#pragma unroll
  for (int off = 32; off > 0; off >>= 1) {
    mse += __shfl_down(mse, off, 64);
    ce  += __shfl_down(ce, off, 64);
  }
  if (lane == 0) { sm[wid] = mse; sc[wid] = ce; }
  __syncthreads();
  if (threadIdx.x == 0) {
    atomicAdd(&wsf[SUM_OFF + 0], sm[0] + sm[1] + sm[2] + sm[3]);
    atomicAdd(&wsf[SUM_OFF + 1], sc[0] + sc[1] + sc[2] + sc[3]);
  }
}

// K4: KL over merged hist + combine.
__global__ __launch_bounds__(256) void k_final(const unsigned* __restrict__ ws,
                                               float* __restrict__ out, int B) {
  const float* wsf = (const float*)ws;
  float male   = (float)ws[CNT_OFF + 0];
  float female = (float)ws[CNT_OFF + 1];
  float local = 0.0f;
  for (int i = threadIdx.x; i < NHCOLS * BINS; i += blockDim.x) {
    float mh  = (float)ws[MH_OFF + i] / male;
    float fh  = (float)ws[FH_OFF + i] / female;
    float mid = 0.5f * (mh + fh);
    if (mh > 0.0f) local += mh * logf((mh + 1e-12f) / (mid + 1e-12f));
    if (fh > 0.0f) local += fh * logf((fh + 1e-12f) / (mid + 1e-12f));
  }
  __shared__ float s[4];
  int lane = threadIdx.x & 63, wid = threadIdx.x >> 6;
#pragma unroll
  for (int off = 32; off > 0; off >>= 1) local += __shfl_down(local, off, 64);
  if (lane == 0) s[wid] = local;
  __syncthreads();
  if (threadIdx.x == 0) {
    float kld   = 0.5f * (s[0] + s[1] + s[2] + s[3]);
    float mse   = wsf[SUM_OFF + 0] / (float)B;
    float ce    = wsf[SUM_OFF + 1] / (float)B;
    float multi = 0.9f * (mse + ce) + 0.1f * kld;
    out[0] = multi;
    out[1] = mse;
    out[2] = ce;
    out[3] = 0.1f * kld;
  }
}

extern "C" void kernel_launch(void* const* d_in, const int* in_sizes, int n_in,
                              void* d_out, int out_size, void* d_ws, size_t ws_size,
                              hipStream_t stream) {
  (void)n_in; (void)out_size; (void)ws_size;
  const float* enc = (const float*)d_in[0];
  const float* dec = (const float*)d_in[1];
  const float* tru = (const float*)d_in[2];
  const float* lab = (const float*)d_in[3];
  const int B = in_sizes[3];                 // label_true is [B,1]
  unsigned* ws = (unsigned*)d_ws;
  float* out = (float*)d_out;

  hipLaunchKernelGGL(k_part, dim3(PB), dim3(256), 0, stream, enc, lab, ws, B);
  hipLaunchKernelGGL(k_reduce, dim3(1), dim3(384), 0, stream, ws);
  hipLaunchKernelGGL(k_fused, dim3((B + 63) / 64), dim3(256), 0, stream,
                     dec, tru, enc, lab, ws, B);
  hipLaunchKernelGGL(k_final, dim3(1), dim3(256), 0, stream, ws, out, B);
}